// Round 2
// baseline (313.046 us; speedup 1.0000x reference)
//
#include <hip/hip_runtime.h>
#include <stdint.h>

typedef unsigned short u16;
typedef unsigned int u32;

#define B_    2
#define HEADS_ 8
#define DK    64
#define T_    2048
#define S_    2048
#define CI    512
#define CO    512
#define E_    512
#define BH_   16

typedef short  short8 __attribute__((ext_vector_type(8)));
typedef __bf16 bf16x8 __attribute__((ext_vector_type(8)));
typedef float  f32x4  __attribute__((ext_vector_type(4)));

static __device__ __forceinline__ u16 f2bf(float f) {
    u32 u = __float_as_uint(f);
    u32 r = (u + 0x7FFFu + ((u >> 16) & 1u)) >> 16;
    return (u16)r;
}

static __device__ __forceinline__ short8 ld8(const u16* p) {
    return *(const short8*)p;
}

static __device__ __forceinline__ f32x4 mfma_bf16(short8 a, short8 b, f32x4 c) {
    return __builtin_amdgcn_mfma_f32_16x16x32_bf16(
        __builtin_bit_cast(bf16x8, a), __builtin_bit_cast(bf16x8, b), c, 0, 0, 0);
}

// ---------------- transpose + cvt: x[b][i][t] f32 -> xt[b][t][i] bf16 ----------------
__global__ __launch_bounds__(256) void k_transpose(const float* __restrict__ x,
                                                   const float* __restrict__ y,
                                                   u16* __restrict__ xt,
                                                   u16* __restrict__ yt) {
    __shared__ float tile[32][33];
    int tsel = blockIdx.z >> 1, b = blockIdx.z & 1;
    const float* src = tsel ? y : x;
    u16* dst = tsel ? yt : xt;
    int t0 = blockIdx.x * 32, i0 = blockIdx.y * 32;
    int tx = threadIdx.x & 31, ty = threadIdx.x >> 5;
#pragma unroll
    for (int r = 0; r < 4; r++) {
        int i = i0 + ty + r * 8;
        tile[ty + r * 8][tx] = src[(size_t)(b * CI + i) * T_ + t0 + tx];
    }
    __syncthreads();
#pragma unroll
    for (int r = 0; r < 4; r++) {
        int t = t0 + ty + r * 8;
        dst[(size_t)(b * T_ + t) * CI + i0 + tx] = f2bf(tile[tx][ty + r * 8]);
    }
}

// ---------------- weight convert f32 -> bf16 (layout preserved) ----------------
__global__ __launch_bounds__(256) void k_wconv(const float* __restrict__ wk, const float* __restrict__ wv,
                                               const float* __restrict__ wq, const float* __restrict__ wf,
                                               u16* __restrict__ wkb, u16* __restrict__ wvb,
                                               u16* __restrict__ wqb, u16* __restrict__ wfb) {
    int idx = blockIdx.x * 256 + threadIdx.x;
    int w = idx >> 18, off = idx & 262143;
    const float* s = (w == 0) ? wk : (w == 1) ? wv : (w == 2) ? wq : wf;
    u16* d = (w == 0) ? wkb : (w == 1) ? wvb : (w == 2) ? wqb : wfb;
    d[off] = f2bf(s[off]);
}

// ---------------- projection GEMM: D[t][e] = sum_i XT[b][t][i] * W[e][i] ----------------
// mode 0: store dst[bh][t][k]  (k = e & 63)     -- for K and Q
// mode 1: store dst[bh][v][t]  (v = e & 63)     -- for V
__global__ __launch_bounds__(256) void k_proj(const u16* __restrict__ xt, const u16* __restrict__ wb,
                                              u16* __restrict__ dst, int mode) {
    int w = blockIdx.x * 4 + (threadIdx.x >> 6);
    int lane = threadIdx.x & 63;
    int col = lane & 15, q = lane >> 4;
    int et = w & 7, tt = (w >> 3) & 127, b = w >> 10;
    int e0 = et * 64, t0 = tt * 16;
    const u16* ap  = xt + (size_t)(b * T_ + t0 + col) * CI + q * 8;
    const u16* bp0 = wb + (size_t)(e0 + col) * CI + q * 8;
    f32x4 acc[4] = {};
#pragma unroll 4
    for (int ks = 0; ks < 16; ks++) {
        short8 a = ld8(ap + ks * 32);
#pragma unroll
        for (int nt = 0; nt < 4; nt++) {
            short8 bb = ld8(bp0 + (size_t)nt * 16 * CI + ks * 32);
            acc[nt] = mfma_bf16(a, bb, acc[nt]);
        }
    }
    int bh = b * 8 + et;
    if (mode == 0) {
#pragma unroll
        for (int nt = 0; nt < 4; nt++)
#pragma unroll
            for (int r = 0; r < 4; r++) {
                int t = t0 + q * 4 + r, k = nt * 16 + col;
                dst[(size_t)(bh * T_ + t) * DK + k] = f2bf(acc[nt][r]);
            }
    } else {
#pragma unroll
        for (int nt = 0; nt < 4; nt++) {
            int v = nt * 16 + col;
            uint2 pk;
            pk.x = f2bf(acc[nt][0]) | ((u32)f2bf(acc[nt][1]) << 16);
            pk.y = f2bf(acc[nt][2]) | ((u32)f2bf(acc[nt][3]) << 16);
            *(uint2*)(dst + (size_t)(bh * DK + v) * T_ + t0 + q * 4) = pk;
        }
    }
}

// ---------------- flash attention ----------------
// scores[t][s] = sum_k K[bh][t][k] * Q[bh][s][k]; softmax over t; O[s][v] += p*V
__global__ __launch_bounds__(256) void k_attn(const u16* __restrict__ kt, const u16* __restrict__ qt,
                                              const u16* __restrict__ vt, const float* __restrict__ mask,
                                              u16* __restrict__ oa) {
    __shared__ u16 Pl[4][16][40];   // per-wave P tile [s][t32], pitch 40 u16 = 80 B (16B-aligned rows)
    __shared__ float Al[4][16];     // per-wave per-s broadcast (alpha, then 1/l)
    int wv = threadIdx.x >> 6, lane = threadIdx.x & 63;
    int col = lane & 15, q = lane >> 4;
    int bh = blockIdx.x >> 5;
    int s_base = (blockIdx.x & 31) * 64 + wv * 16;
    int sg = s_base + col;
    const u16* qp = qt + (size_t)(bh * S_ + sg) * DK + q * 8;
    short8 bq0 = ld8(qp), bq1 = ld8(qp + 32);
    float m_run = -1e30f, l_run = 0.f;
    f32x4 oacc[4] = {};
    const float sc = 0.125f * 1.44269504088896f;  // scale * log2(e)
    for (int t0 = 0; t0 < T_; t0 += 32) {
        f32x4 scf[2];
#pragma unroll
        for (int st = 0; st < 2; st++) {
            const u16* kp = kt + (size_t)(bh * T_ + t0 + st * 16 + col) * DK + q * 8;
            f32x4 z = {};
            scf[st] = mfma_bf16(ld8(kp), bq0, z);
            scf[st] = mfma_bf16(ld8(kp + 32), bq1, scf[st]);
        }
        float vals[8];
        float mx = -1e30f;
#pragma unroll
        for (int st = 0; st < 2; st++)
#pragma unroll
            for (int r = 0; r < 4; r++) {
                int t = t0 + st * 16 + q * 4 + r;
                float vvv = (scf[st][r] + mask[(size_t)t * S_ + sg]) * sc;
                vals[st * 4 + r] = vvv;
                mx = fmaxf(mx, vvv);
            }
        mx = fmaxf(mx, __shfl_xor(mx, 16));
        mx = fmaxf(mx, __shfl_xor(mx, 32));
        float m_new = fmaxf(m_run, mx);
        float alpha = __builtin_amdgcn_exp2f(m_run - m_new);
        float ps = 0.f;
        u16 pb[8];
#pragma unroll
        for (int i = 0; i < 8; i++) {
            float p = __builtin_amdgcn_exp2f(vals[i] - m_new);
            ps += p;
            pb[i] = f2bf(p);
        }
        ps += __shfl_xor(ps, 16);
        ps += __shfl_xor(ps, 32);
        l_run = l_run * alpha + ps;
        m_run = m_new;
#pragma unroll
        for (int st = 0; st < 2; st++) {
            uint2 pk;
            pk.x = pb[st * 4 + 0] | ((u32)pb[st * 4 + 1] << 16);
            pk.y = pb[st * 4 + 2] | ((u32)pb[st * 4 + 3] << 16);
            *(uint2*)&Pl[wv][col][st * 16 + q * 4] = pk;
        }
        Al[wv][col] = alpha;
        __syncthreads();
        float4 ar = *(const float4*)&Al[wv][q * 4];
        short8 pa = ld8(&Pl[wv][col][q * 8]);
#pragma unroll
        for (int nt = 0; nt < 4; nt++) {
            const u16* vp = vt + (size_t)(bh * DK + nt * 16 + col) * T_ + t0 + q * 8;
            short8 vb = ld8(vp);
            oacc[nt][0] *= ar.x; oacc[nt][1] *= ar.y; oacc[nt][2] *= ar.z; oacc[nt][3] *= ar.w;
            oacc[nt] = mfma_bf16(pa, vb, oacc[nt]);
        }
        __syncthreads();
    }
    Al[wv][col] = 1.f / l_run;
    __syncthreads();
    float4 lr = *(const float4*)&Al[wv][q * 4];
    int b = bh >> 3, h = bh & 7;
#pragma unroll
    for (int nt = 0; nt < 4; nt++)
#pragma unroll
        for (int r = 0; r < 4; r++) {
            int s = s_base + q * 4 + r;
            float lv = (r == 0) ? lr.x : (r == 1) ? lr.y : (r == 2) ? lr.z : lr.w;
            oa[(size_t)(b * S_ + s) * E_ + h * DK + nt * 16 + col] = f2bf(oacc[nt][r] * lv);
        }
}

// ---------------- final GEMM: out[b][s][o] = sum_v OA[b][s][v] * W[o][v] + bias[o] ----------------
__global__ __launch_bounds__(256) void k_final(const u16* __restrict__ oa, const u16* __restrict__ wfb,
                                               const float* __restrict__ bias, float* __restrict__ out) {
    int w = blockIdx.x * 4 + (threadIdx.x >> 6);
    int lane = threadIdx.x & 63;
    int col = lane & 15, q = lane >> 4;
    int ot = w & 7, stt = (w >> 3) & 127, b = w >> 10;
    int o0 = ot * 64, s0 = stt * 16;
    const u16* ap = oa + (size_t)(b * S_ + s0 + col) * E_ + q * 8;
    const u16* bp = wfb + (size_t)(o0 + col) * E_ + q * 8;
    f32x4 acc[4] = {};
#pragma unroll 4
    for (int ks = 0; ks < 16; ks++) {
        short8 a = ld8(ap + ks * 32);
#pragma unroll
        for (int nt = 0; nt < 4; nt++) {
            acc[nt] = mfma_bf16(a, ld8(bp + (size_t)nt * 16 * E_ + ks * 32), acc[nt]);
        }
    }
#pragma unroll
    for (int nt = 0; nt < 4; nt++) {
        float bn = bias[o0 + nt * 16 + col];
#pragma unroll
        for (int r = 0; r < 4; r++) {
            int s = s0 + q * 4 + r;
            out[(size_t)(b * S_ + s) * CO + o0 + nt * 16 + col] = acc[nt][r] + bn;
        }
    }
}

extern "C" void kernel_launch(void* const* d_in, const int* in_sizes, int n_in,
                              void* d_out, int out_size, void* d_ws, size_t ws_size,
                              hipStream_t stream) {
    const float* x    = (const float*)d_in[0];
    const float* y    = (const float*)d_in[1];
    const float* mask = (const float*)d_in[2];
    const float* Wk   = (const float*)d_in[3];
    const float* Wv   = (const float*)d_in[4];
    const float* Wq   = (const float*)d_in[5];
    const float* Wf   = (const float*)d_in[6];
    const float* bias = (const float*)d_in[7];
    float* out = (float*)d_out;

    // Compact aliased layout — peak 18 MiB (ws overrun in round 0 corrupted
    // adjacent allocations -> post-timing divergence).
    u16* ws = (u16*)d_ws;
    u16* XT  = ws;                 // [0, 2M) u16          x^T bf16; later reused as OA
    u16* YT  = XT + 2097152;       // [2M, 4M)             y^T bf16; later reused as VT
    u16* WKB = YT + 2097152;       // [4M, 4.25M)
    u16* WVB = WKB + 262144;
    u16* WQB = WVB + 262144;
    u16* WFB = WQB + 262144;
    u16* KT  = WFB + 262144;       // [5M, 7M)
    u16* QT  = KT + 2097152;       // [7M, 9M)   end = 9M u16 = 18 MiB
    u16* VT  = YT;                 // alias: YT dead after projQ
    u16* OA  = XT;                 // alias: XT dead after projK/projV

    k_transpose<<<dim3(64, 16, 4), 256, 0, stream>>>(x, y, XT, YT);
    k_wconv<<<4096, 256, 0, stream>>>(Wk, Wv, Wq, Wf, WKB, WVB, WQB, WFB);
    k_proj<<<512, 256, 0, stream>>>(YT, WQB, QT, 0);   // queries first (frees YT)
    k_proj<<<512, 256, 0, stream>>>(XT, WKB, KT, 0);
    k_proj<<<512, 256, 0, stream>>>(XT, WVB, VT, 1);   // VT overwrites YT (safe)
    k_attn<<<512, 256, 0, stream>>>(KT, QT, VT, mask, OA);  // OA overwrites XT (safe)
    k_final<<<512, 256, 0, stream>>>(OA, WFB, bias, out);
}

// Round 3
// 266.250 us; speedup vs baseline: 1.1758x; 1.1758x over previous
//
#include <hip/hip_runtime.h>
#include <stdint.h>

typedef unsigned short u16;
typedef unsigned int u32;

#define B_    2
#define DK    64
#define T_    2048
#define S_    2048
#define CI    512
#define CO    512
#define E_    512

typedef short  short8 __attribute__((ext_vector_type(8)));
typedef __bf16 bf16x8 __attribute__((ext_vector_type(8)));
typedef float  f32x4  __attribute__((ext_vector_type(4)));

static __device__ __forceinline__ u16 f2bf(float f) {
    u32 u = __float_as_uint(f);
    u32 r = (u + 0x7FFFu + ((u >> 16) & 1u)) >> 16;
    return (u16)r;
}

static __device__ __forceinline__ short8 ld8(const u16* p) {
    return *(const short8*)p;
}

static __device__ __forceinline__ f32x4 mfma_bf16(short8 a, short8 b, f32x4 c) {
    return __builtin_amdgcn_mfma_f32_16x16x32_bf16(
        __builtin_bit_cast(bf16x8, a), __builtin_bit_cast(bf16x8, b), c, 0, 0, 0);
}

// ---------------- transpose + cvt: x[b][i][t] f32 -> xt[b][t][i] bf16 ----------------
__global__ __launch_bounds__(256) void k_transpose(const float* __restrict__ x,
                                                   const float* __restrict__ y,
                                                   u16* __restrict__ xt,
                                                   u16* __restrict__ yt) {
    __shared__ float tile[32][33];
    int tsel = blockIdx.z >> 1, b = blockIdx.z & 1;
    const float* src = tsel ? y : x;
    u16* dst = tsel ? yt : xt;
    int t0 = blockIdx.x * 32, i0 = blockIdx.y * 32;
    int tx = threadIdx.x & 31, ty = threadIdx.x >> 5;
#pragma unroll
    for (int r = 0; r < 4; r++) {
        int i = i0 + ty + r * 8;
        tile[ty + r * 8][tx] = src[(size_t)(b * CI + i) * T_ + t0 + tx];
    }
    __syncthreads();
#pragma unroll
    for (int r = 0; r < 4; r++) {
        int t = t0 + ty + r * 8;
        dst[(size_t)(b * T_ + t) * CI + i0 + tx] = f2bf(tile[tx][ty + r * 8]);
    }
}

// ---------------- weight convert f32 -> bf16 ----------------
__global__ __launch_bounds__(256) void k_wconv(const float* __restrict__ wk, const float* __restrict__ wv,
                                               const float* __restrict__ wq, const float* __restrict__ wf,
                                               u16* __restrict__ wkb, u16* __restrict__ wvb,
                                               u16* __restrict__ wqb, u16* __restrict__ wfb) {
    int idx = blockIdx.x * 256 + threadIdx.x;
    int w = idx >> 18, off = idx & 262143;
    const float* s = (w == 0) ? wk : (w == 1) ? wv : (w == 2) ? wq : wf;
    u16* d = (w == 0) ? wkb : (w == 1) ? wvb : (w == 2) ? wqb : wfb;
    d[off] = f2bf(s[off]);
}

// ---------------- fused projection GEMMs ----------------
// p = p_base + (blockIdx.x>>8): 0=Q (yt->QT m0), 1=K (xt->KT m0), 2=V (xt->VT m1)
// block tile 64t x 128e, wave tile 32t x 64e
__global__ __launch_bounds__(256) void k_proj3(const u16* __restrict__ xt, const u16* __restrict__ yt,
                                               const u16* __restrict__ wkb, const u16* __restrict__ wvb,
                                               const u16* __restrict__ wqb,
                                               u16* __restrict__ ktd, u16* __restrict__ vtd,
                                               u16* __restrict__ qtd, int p_base) {
    int bi = blockIdx.x;
    int p = p_base + (bi >> 8);
    int r = bi & 255;
    int et = r & 3, tt = r >> 2;          // et: 128-e tile, tt: 64-t tile (b folded)
    int wv = threadIdx.x >> 6, lane = threadIdx.x & 63;
    int col = lane & 15, q = lane >> 4;
    int b = tt >> 5;
    int t0 = (tt & 31) * 64 + (wv >> 1) * 32;
    int e0 = et * 128 + (wv & 1) * 64;
    const u16* src = (p == 0) ? yt : xt;
    const u16* wb  = (p == 0) ? wqb : (p == 1) ? wkb : wvb;
    const u16* ap0 = src + (size_t)(b * T_ + t0 + col) * CI + q * 8;
    const u16* bp0 = wb + (size_t)(e0 + col) * CI + q * 8;
    f32x4 acc[2][4] = {};
#pragma unroll 4
    for (int ks = 0; ks < 16; ks++) {
        short8 a0 = ld8(ap0 + ks * 32);
        short8 a1 = ld8(ap0 + 16 * CI + ks * 32);
#pragma unroll
        for (int nt = 0; nt < 4; nt++) {
            short8 bb = ld8(bp0 + (size_t)(nt * 16) * CI + ks * 32);
            acc[0][nt] = mfma_bf16(a0, bb, acc[0][nt]);
            acc[1][nt] = mfma_bf16(a1, bb, acc[1][nt]);
        }
    }
    u16* dst = (p == 0) ? qtd : (p == 1) ? ktd : vtd;
    if (p < 2) {
#pragma unroll
        for (int mt = 0; mt < 2; mt++)
#pragma unroll
            for (int nt = 0; nt < 4; nt++) {
                int e = e0 + nt * 16 + col, h = e >> 6, k = e & 63;
                u16* dp = dst + ((size_t)(b * 8 + h) * T_ + t0 + mt * 16 + q * 4) * DK + k;
                dp[0] = f2bf(acc[mt][nt][0]);
                dp[DK] = f2bf(acc[mt][nt][1]);
                dp[2 * DK] = f2bf(acc[mt][nt][2]);
                dp[3 * DK] = f2bf(acc[mt][nt][3]);
            }
    } else {
#pragma unroll
        for (int mt = 0; mt < 2; mt++)
#pragma unroll
            for (int nt = 0; nt < 4; nt++) {
                int e = e0 + nt * 16 + col, h = e >> 6, v = e & 63;
                uint2 pk;
                pk.x = f2bf(acc[mt][nt][0]) | ((u32)f2bf(acc[mt][nt][1]) << 16);
                pk.y = f2bf(acc[mt][nt][2]) | ((u32)f2bf(acc[mt][nt][3]) << 16);
                *(uint2*)(dst + ((size_t)(b * 8 + h) * DK + v) * T_ + t0 + mt * 16 + q * 4) = pk;
            }
    }
}

// ---------------- flash attention (barrier-free; waves independent) ----------------
__global__ __launch_bounds__(256) void k_attn(const u16* __restrict__ kt, const u16* __restrict__ qt,
                                              const u16* __restrict__ vt, const float* __restrict__ mask,
                                              u16* __restrict__ oa) {
    __shared__ u16 Pl[4][16][40];   // per-wave P tile [s16][t32], pitch 80B (16B-aligned rows)
    __shared__ float Al[4][16];     // per-wave per-s broadcast
    int wv = threadIdx.x >> 6, lane = threadIdx.x & 63;
    int col = lane & 15, q = lane >> 4;
    int bh = blockIdx.x >> 5;
    int s_base = (blockIdx.x & 31) * 64 + wv * 16;
    int sg = s_base + col;
    const u16* qp = qt + (size_t)(bh * S_ + sg) * DK + q * 8;
    short8 bq0 = ld8(qp), bq1 = ld8(qp + 32);
    const u16* kbase = kt + (size_t)bh * T_ * DK + (size_t)col * DK + q * 8;
    const u16* vbase = vt + (size_t)bh * DK * T_ + (size_t)col * T_ + q * 8;
    const float* mbase = mask + sg;
    float m_run = -1e30f, l_run = 0.f;
    f32x4 oacc[4] = {};
    const float sc = 0.125f * 1.44269504088896f;  // scale * log2(e)

    // prologue: loads for t0 = 0
    short8 ka[2][2];
    float mpre[8];
#pragma unroll
    for (int st = 0; st < 2; st++) {
        const u16* kp = kbase + (size_t)(st * 16) * DK;
        ka[st][0] = ld8(kp);
        ka[st][1] = ld8(kp + 32);
#pragma unroll
        for (int r = 0; r < 4; r++)
            mpre[st * 4 + r] = mbase[(size_t)(st * 16 + q * 4 + r) * S_] * sc;
    }

    for (int t0 = 0; t0 < T_; t0 += 32) {
        // prefetch next K tile + mask (latency overlapped with softmax below)
        short8 kn[2][2];
        float mn[8];
        int t1 = t0 + 32;
        if (t1 < T_) {
#pragma unroll
            for (int st = 0; st < 2; st++) {
                const u16* kp = kbase + (size_t)(t1 + st * 16) * DK;
                kn[st][0] = ld8(kp);
                kn[st][1] = ld8(kp + 32);
#pragma unroll
                for (int r = 0; r < 4; r++)
                    mn[st * 4 + r] = mbase[(size_t)(t1 + st * 16 + q * 4 + r) * S_] * sc;
            }
        }
        // V loads for current tile (independent of softmax chain)
        short8 vb[4];
#pragma unroll
        for (int nt = 0; nt < 4; nt++)
            vb[nt] = ld8(vbase + (size_t)(nt * 16) * T_ + t0);

        f32x4 scf[2];
#pragma unroll
        for (int st = 0; st < 2; st++) {
            f32x4 z = {};
            scf[st] = mfma_bf16(ka[st][0], bq0, z);
            scf[st] = mfma_bf16(ka[st][1], bq1, scf[st]);
        }
        float vals[8];
        float mx = -1e30f;
#pragma unroll
        for (int i = 0; i < 8; i++) {
            float vvv = fmaf(scf[i >> 2][i & 3], sc, mpre[i]);
            vals[i] = vvv;
            mx = fmaxf(mx, vvv);
        }
        mx = fmaxf(mx, __shfl_xor(mx, 16));
        mx = fmaxf(mx, __shfl_xor(mx, 32));
        float m_new = fmaxf(m_run, mx);
        float alpha = __builtin_amdgcn_exp2f(m_run - m_new);
        float ps = 0.f;
        u16 pb[8];
#pragma unroll
        for (int i = 0; i < 8; i++) {
            float p = __builtin_amdgcn_exp2f(vals[i] - m_new);
            ps += p;
            pb[i] = f2bf(p);
        }
        ps += __shfl_xor(ps, 16);
        ps += __shfl_xor(ps, 32);
        l_run = l_run * alpha + ps;
        m_run = m_new;
        // wave-local LDS round-trip: C/D layout -> A-operand layout (no block barrier:
        // all Pl/Al traffic is within this wave; DS ops complete in-order per wave)
#pragma unroll
        for (int st = 0; st < 2; st++) {
            uint2 pk;
            pk.x = pb[st * 4 + 0] | ((u32)pb[st * 4 + 1] << 16);
            pk.y = pb[st * 4 + 2] | ((u32)pb[st * 4 + 3] << 16);
            *(uint2*)&Pl[wv][col][st * 16 + q * 4] = pk;
        }
        Al[wv][col] = alpha;
        __builtin_amdgcn_wave_barrier();
        float4 ar = *(const float4*)&Al[wv][q * 4];
        short8 pa = ld8(&Pl[wv][col][q * 8]);
#pragma unroll
        for (int nt = 0; nt < 4; nt++) {
            oacc[nt][0] *= ar.x; oacc[nt][1] *= ar.y; oacc[nt][2] *= ar.z; oacc[nt][3] *= ar.w;
            oacc[nt] = mfma_bf16(pa, vb[nt], oacc[nt]);
        }
        __builtin_amdgcn_wave_barrier();
#pragma unroll
        for (int st = 0; st < 2; st++) {
            ka[st][0] = kn[st][0];
            ka[st][1] = kn[st][1];
        }
#pragma unroll
        for (int i = 0; i < 8; i++) mpre[i] = mn[i];
    }
    Al[wv][col] = 1.f / l_run;
    __builtin_amdgcn_wave_barrier();
    float4 lr = *(const float4*)&Al[wv][q * 4];
    int b = bh >> 3, h = bh & 7;
#pragma unroll
    for (int nt = 0; nt < 4; nt++)
#pragma unroll
        for (int r = 0; r < 4; r++) {
            int s = s_base + q * 4 + r;
            float lv = (r == 0) ? lr.x : (r == 1) ? lr.y : (r == 2) ? lr.z : lr.w;
            oa[(size_t)(b * S_ + s) * E_ + h * DK + nt * 16 + col] = f2bf(oacc[nt][r] * lv);
        }
}

// ---------------- final GEMM: out[b][s][o] = sum_v OA[b][s][v] * W[o][v] + bias[o] ----------------
// block tile 64s x 128o, wave tile 32s x 64o
__global__ __launch_bounds__(256) void k_final(const u16* __restrict__ oa, const u16* __restrict__ wfb,
                                               const float* __restrict__ bias, float* __restrict__ out) {
    int bi = blockIdx.x;
    int et = bi & 3, tt = bi >> 2;
    int wv = threadIdx.x >> 6, lane = threadIdx.x & 63;
    int col = lane & 15, q = lane >> 4;
    int b = tt >> 5;
    int s0 = (tt & 31) * 64 + (wv >> 1) * 32;
    int o0 = et * 128 + (wv & 1) * 64;
    const u16* ap0 = oa + (size_t)(b * S_ + s0 + col) * E_ + q * 8;
    const u16* bp0 = wfb + (size_t)(o0 + col) * E_ + q * 8;
    f32x4 acc[2][4] = {};
#pragma unroll 4
    for (int ks = 0; ks < 16; ks++) {
        short8 a0 = ld8(ap0 + ks * 32);
        short8 a1 = ld8(ap0 + 16 * E_ + ks * 32);
#pragma unroll
        for (int nt = 0; nt < 4; nt++) {
            short8 bb = ld8(bp0 + (size_t)(nt * 16) * E_ + ks * 32);
            acc[0][nt] = mfma_bf16(a0, bb, acc[0][nt]);
            acc[1][nt] = mfma_bf16(a1, bb, acc[1][nt]);
        }
    }
#pragma unroll
    for (int mt = 0; mt < 2; mt++)
#pragma unroll
        for (int nt = 0; nt < 4; nt++) {
            int o = o0 + nt * 16 + col;
            float bn = bias[o];
#pragma unroll
            for (int r = 0; r < 4; r++) {
                int s = s0 + mt * 16 + q * 4 + r;
                out[(size_t)(b * S_ + s) * CO + o] = acc[mt][nt][r] + bn;
            }
        }
}

extern "C" void kernel_launch(void* const* d_in, const int* in_sizes, int n_in,
                              void* d_out, int out_size, void* d_ws, size_t ws_size,
                              hipStream_t stream) {
    const float* x    = (const float*)d_in[0];
    const float* y    = (const float*)d_in[1];
    const float* mask = (const float*)d_in[2];
    const float* Wk   = (const float*)d_in[3];
    const float* Wv   = (const float*)d_in[4];
    const float* Wq   = (const float*)d_in[5];
    const float* Wf   = (const float*)d_in[6];
    const float* bias = (const float*)d_in[7];
    float* out = (float*)d_out;

    // Compact aliased layout — peak 18 MiB.
    u16* ws = (u16*)d_ws;
    u16* XT  = ws;                 // x^T bf16; reused as OA after projections
    u16* YT  = XT + 2097152;       // y^T bf16; reused as VT after Q projection
    u16* WKB = YT + 2097152;
    u16* WVB = WKB + 262144;
    u16* WQB = WVB + 262144;
    u16* WFB = WQB + 262144;
    u16* KT  = WFB + 262144;
    u16* QT  = KT + 2097152;       // end = 18 MiB
    u16* VT  = YT;                 // alias: YT dead after Q proj (launch 1)
    u16* OA  = XT;                 // alias: XT dead after K/V proj

    k_transpose<<<dim3(64, 16, 4), 256, 0, stream>>>(x, y, XT, YT);
    k_wconv<<<4096, 256, 0, stream>>>(Wk, Wv, Wq, Wf, WKB, WVB, WQB, WFB);
    // launch 1: Q (reads YT) + K (reads XT)
    k_proj3<<<512, 256, 0, stream>>>(XT, YT, WKB, WVB, WQB, KT, VT, QT, 0);
    // launch 2: V (reads XT, writes VT == YT — safe, launch 1 done with YT)
    k_proj3<<<256, 256, 0, stream>>>(XT, YT, WKB, WVB, WQB, KT, VT, QT, 2);
    k_attn<<<512, 256, 0, stream>>>(KT, QT, VT, mask, OA);
    k_final<<<256, 256, 0, stream>>>(OA, WFB, bias, out);
}